// Round 4
// baseline (599.655 us; speedup 1.0000x reference)
//
#include <hip/hip_runtime.h>

// Problem constants (fixed by reference)
constexpr int B_ROWS = 65536;
constexpr int IN_F   = 1024;
constexpr int OUT_F  = 1024;

constexpr int BDIM = 512;            // 8 waves
constexpr int BM = 256, BN = 256, BK = 64;

typedef __bf16 bf16x8 __attribute__((ext_vector_type(8)));
typedef float  f32x4  __attribute__((ext_vector_type(4)));

__device__ __forceinline__ bf16x8 cvt8(f32x4 u0, f32x4 u1) {
    bf16x8 v;
    v[0] = (__bf16)u0[0]; v[1] = (__bf16)u0[1]; v[2] = (__bf16)u0[2]; v[3] = (__bf16)u0[3];
    v[4] = (__bf16)u1[0]; v[5] = (__bf16)u1[1]; v[6] = (__bf16)u1[2]; v[7] = (__bf16)u1[3];
    return v;
}

// async global->LDS, 16B per lane (wave stages 1KB contiguous at uniform lds base)
__device__ __forceinline__ void glds16(const __bf16* g, unsigned char* l) {
    __builtin_amdgcn_global_load_lds(
        (const __attribute__((address_space(1))) unsigned int*)(const void*)g,
        (__attribute__((address_space(3))) unsigned int*)(void*)l,
        16, 0, 0);
}

// ---------------- f32 -> bf16 convert: X (16384 blocks) + W (256 blocks) ------------
__global__ __launch_bounds__(256)
void cvt_all(const float* __restrict__ X, const float* __restrict__ W,
             __bf16* __restrict__ Xb, __bf16* __restrict__ Wb) {
    const int b = blockIdx.x;
    const float* in;
    __bf16* out;
    size_t i;
    if (b < 16384) { in = X; out = Xb; i = ((size_t)b * 256 + threadIdx.x) * 16; }
    else           { in = W; out = Wb; i = ((size_t)(b - 16384) * 256 + threadIdx.x) * 16; }
    f32x4 a0 = *(const f32x4*)(in + i);
    f32x4 a1 = *(const f32x4*)(in + i + 4);
    f32x4 a2 = *(const f32x4*)(in + i + 8);
    f32x4 a3 = *(const f32x4*)(in + i + 12);
    *(bf16x8*)(out + i)     = cvt8(a0, a1);
    *(bf16x8*)(out + i + 8) = cvt8(a2, a3);
}

// ---------------- 256x256, BK=64, 8-wave, faithful 8-phase template GEMM -------------
// LDS buffer (64KB): A kh0 [0,16K) kh1 [16K,32K), B kh0 [32K,48K) kh1 [48K,64K).
// Each 16KB quadrant = 16 MFMA-order 1KB blocks (block bi = rows 16bi..16bi+15;
// lane l <-> row 16bi+(l&15), k-elems (l>>4)*8..+8, byte l*16). Wave w stages
// blocks {2w,2w+1} of each quadrant (2 glds16, uniform LDS dst, per-lane src).
// Per phase: 2 glds (staggered so every load has >=5 phases in flight), 4-8
// ds_read_b128, barrier, 16 MFMA (setprio-wrapped), barrier. End-of-round wait
// = vmcnt(4): retires tile t+1 fully, leaves tile t+2's kh0 (4 loads) in flight.
__global__ __launch_bounds__(BDIM, 2)
void fused_linear_act(const __bf16* __restrict__ Xb,  // [B_ROWS][IN_F] bf16
                      const __bf16* __restrict__ Wb,  // [OUT_F][IN_F] bf16
                      const float* __restrict__ bias, // [OUT_F]
                      float* __restrict__ O)          // [B_ROWS][OUT_F]
{
    __shared__ __attribute__((aligned(16))) unsigned char lds[2 * 65536];  // 128 KB

    const int bx  = blockIdx.x;                 // 1024 blocks
    // XCD-aware: 4 consecutive blocks per XCD share one A panel (L2 reuse).
    const int xcd = bx & 7;
    const int idx = bx >> 3;
    const int nt  = idx & 3;
    const int mt  = xcd + 8 * (idx >> 2);
    const int m0 = mt * BM;
    const int n0 = nt * BN;

    const int tid  = threadIdx.x;
    const int lane = tid & 63;
    const int wave = tid >> 6;                  // 0..7, 2M x 4N
    const int wr2  = wave >> 2;                 // m-half of output
    const int w4   = wave & 3;                  // n-quarter of output
    const int lrow = lane & 15;
    const int quad = lane >> 4;

    // staging global sources (per-lane, MFMA-order pre-swizzle)
    const __bf16* agp = Xb + (size_t)(m0 + 32 * wave + lrow) * IN_F + quad * 8;
    const __bf16* bgp = Wb + (size_t)(n0 + 32 * wave + lrow) * IN_F + quad * 8;

    unsigned char* const b0 = lds;
    unsigned char* const b1 = lds + 65536;

    f32x4 acc[8][4];
    #pragma unroll
    for (int i = 0; i < 8; ++i)
        #pragma unroll
        for (int j = 0; j < 4; ++j)
            acc[i][j] = (f32x4){0.f, 0.f, 0.f, 0.f};

    bf16x8 aq0, aq1, aq2, aq3, bq0, bq1, bq2, bq3;

// stage: wave's 2 blocks of quadrant (operand, KH) at global k-offset K
#define GA(BUF, KH, K) do { unsigned char* _d = (BUF) + (KH) * 16384 + wave * 2048; \
    glds16(agp + (K), _d); glds16(agp + (K) + 16 * IN_F, _d + 1024); } while (0)
#define GB(BUF, KH, K) do { unsigned char* _d = (BUF) + 32768 + (KH) * 16384 + wave * 2048; \
    glds16(bgp + (K), _d); glds16(bgp + (K) + 16 * IN_F, _d + 1024); } while (0)
// fragment reads for this wave's output sub-tile
#define RA(BUF, KH, MH) do { \
    const unsigned char* _r = (BUF) + (KH) * 16384 + (wr2 * 8 + (MH) * 4) * 1024 + lane * 16; \
    aq0 = *(const bf16x8*)(_r);        aq1 = *(const bf16x8*)(_r + 1024); \
    aq2 = *(const bf16x8*)(_r + 2048); aq3 = *(const bf16x8*)(_r + 3072); } while (0)
#define RB(BUF, KH) do { \
    const unsigned char* _r = (BUF) + 32768 + (KH) * 16384 + (w4 * 4) * 1024 + lane * 16; \
    bq0 = *(const bf16x8*)(_r);        bq1 = *(const bf16x8*)(_r + 1024); \
    bq2 = *(const bf16x8*)(_r + 2048); bq3 = *(const bf16x8*)(_r + 3072); } while (0)
#define MFMA1(MH, I, J) acc[(MH)*4+(I)][(J)] = \
    __builtin_amdgcn_mfma_f32_16x16x32_bf16(aq##I, bq##J, acc[(MH)*4+(I)][(J)], 0, 0, 0)
#define MFMAQ(MH) do { __builtin_amdgcn_s_setprio(1); \
    MFMA1(MH,0,0); MFMA1(MH,0,1); MFMA1(MH,0,2); MFMA1(MH,0,3); \
    MFMA1(MH,1,0); MFMA1(MH,1,1); MFMA1(MH,1,2); MFMA1(MH,1,3); \
    MFMA1(MH,2,0); MFMA1(MH,2,1); MFMA1(MH,2,2); MFMA1(MH,2,3); \
    MFMA1(MH,3,0); MFMA1(MH,3,1); MFMA1(MH,3,2); MFMA1(MH,3,3); \
    __builtin_amdgcn_s_setprio(0); } while (0)
#define BAR() __builtin_amdgcn_s_barrier()
#define VM4() asm volatile("s_waitcnt vmcnt(4)" ::: "memory")
#define VM0() asm volatile("s_waitcnt vmcnt(0)" ::: "memory")

// Steady round t (tile t in CUR = buf t&1): stage (t+1,kh1)->OPP at P0/P1,
// (t+2,kh0)->CUR at P2/P3 (those slots were fully consumed by P1).
#define ROUND_S(CUR, OPP, KT) do { \
    /* P0 */ GA(OPP, 1, ((KT) + 1) * 64 + 32); RB(CUR, 0); RA(CUR, 0, 0); \
             BAR(); MFMAQ(0); BAR(); \
    /* P1 */ GB(OPP, 1, ((KT) + 1) * 64 + 32); RA(CUR, 0, 1); \
             BAR(); MFMAQ(1); BAR(); \
    /* P2 */ GA(CUR, 0, ((KT) + 2) * 64); RB(CUR, 1); RA(CUR, 1, 0); \
             BAR(); MFMAQ(0); BAR(); \
    /* P3 */ GB(CUR, 0, ((KT) + 2) * 64); RA(CUR, 1, 1); \
             BAR(); MFMAQ(1); VM4(); BAR(); \
} while (0)

    // Prologue: tile0 fully staged into b0; tile1 kh0 into b1; retire tile0 only.
    GA(b0, 0, 0);  GB(b0, 0, 0);
    GA(b0, 1, 32); GB(b0, 1, 32);
    GA(b1, 0, 64); GB(b1, 0, 64);
    VM4();          // tile0's 8 retired; tile1-kh0's 4 stay in flight
    BAR();

    #pragma unroll 1
    for (int kt = 0; kt < 14; kt += 2) {
        ROUND_S(b0, b1, kt);
        ROUND_S(b1, b0, kt + 1);
    }
    // Round 14 (tile14 in b0): stage tile15 kh1; no tile16 -> drain at end.
    GA(b1, 1, 15 * 64 + 32); RB(b0, 0); RA(b0, 0, 0); BAR(); MFMAQ(0); BAR();
    GB(b1, 1, 15 * 64 + 32); RA(b0, 0, 1);            BAR(); MFMAQ(1); BAR();
    RB(b0, 1); RA(b0, 1, 0);                          BAR(); MFMAQ(0); BAR();
    RA(b0, 1, 1);                                     BAR(); MFMAQ(1); VM0(); BAR();
    // Round 15 (tile15 in b1): pure compute.
    RB(b1, 0); RA(b1, 0, 0); BAR(); MFMAQ(0); BAR();
    RA(b1, 0, 1);            BAR(); MFMAQ(1); BAR();
    RB(b1, 1); RA(b1, 1, 0); BAR(); MFMAQ(0); BAR();
    RA(b1, 1, 1);            BAR(); MFMAQ(1);

    // Epilogue: bias + cyclic activation; selector = col%4 = lane&3 (branchless)
    const int s = lane & 3;
    const float kmul = (s == 0) ? -2.f : -1.f;
    const float aa   = (s == 0) ?  2.f :  1.f;
    const float cc   = (s == 0) ? -1.f :  0.f;
    const bool  is_sin  = (s == 1);
    const bool  is_relu = (s == 2);

    float bv[4];
    #pragma unroll
    for (int fn = 0; fn < 4; ++fn) bv[fn] = bias[n0 + w4 * 64 + fn * 16 + lrow];

    #pragma unroll
    for (int fm = 0; fm < 8; ++fm) {
        #pragma unroll
        for (int r = 0; r < 4; ++r) {
            const int gr = m0 + wr2 * 128 + fm * 16 + quad * 4 + r;
            float* op = O + (size_t)gr * OUT_F + n0 + w4 * 64 + lrow;
            #pragma unroll
            for (int fn = 0; fn < 4; ++fn) {
                const float y = acc[fm][fn][r] + bv[fn];
                const float e = __expf(kmul * y);
                const float g = fmaf(aa, __builtin_amdgcn_rcpf(1.f + e), cc);
                const float sv = __sinf(y);
                const float rv = fmaxf(y, 0.f);
                const float res = is_sin ? sv : (is_relu ? rv : g);
                op[fn * 16] = res;
            }
        }
    }
}

// ================= fallback (ws too small): round-2 2-phase 128^2 kernel =============
constexpr int FBDIM = 256;
#define FBAR_CNT() asm volatile("s_waitcnt vmcnt(4) lgkmcnt(0)\n\ts_barrier" ::: "memory")
#define FBAR_ALL() asm volatile("s_waitcnt vmcnt(0) lgkmcnt(0)\n\ts_barrier" ::: "memory")

__global__ __launch_bounds__(256)
void w_to_bf16(const float* __restrict__ W, __bf16* __restrict__ Wb) {
    const size_t i = ((size_t)blockIdx.x * 256 + threadIdx.x) * 16;
    f32x4 a0 = *(const f32x4*)(W + i);
    f32x4 a1 = *(const f32x4*)(W + i + 4);
    f32x4 a2 = *(const f32x4*)(W + i + 8);
    f32x4 a3 = *(const f32x4*)(W + i + 12);
    *(bf16x8*)(Wb + i)     = cvt8(a0, a1);
    *(bf16x8*)(Wb + i + 8) = cvt8(a2, a3);
}

__global__ __launch_bounds__(FBDIM, 4)
void fused_linear_act_f32a(const float* __restrict__ X,
                           const __bf16* __restrict__ Wb,
                           const float* __restrict__ bias,
                           float* __restrict__ O)
{
    __shared__ __attribute__((aligned(16))) unsigned char lds[2 * 16384];
    const int bx  = blockIdx.x;
    const int xcd = bx & 7;
    const int idx = bx >> 3;
    const int nt  = idx & 7;
    const int mt  = xcd + 8 * (idx >> 3);
    const int m0 = mt * 128;
    const int n0 = nt * 128;
    const int tid  = threadIdx.x;
    const int lane = tid & 63;
    const int wave = tid >> 6;
    const int wm = (wave >> 1) * 64;
    const int wn = (wave & 1) * 64;
    const int lrow = lane & 15;
    const int quad = lane >> 4;
    const int srow = tid >> 2;
    const int sseg = tid & 3;

    f32x4 acc[4][4];
    #pragma unroll
    for (int i = 0; i < 4; ++i)
        #pragma unroll
        for (int j = 0; j < 4; ++j)
            acc[i][j] = (f32x4){0.f, 0.f, 0.f, 0.f};

    const float* xa = X + (size_t)(m0 + srow) * IN_F + sseg * 8;
    const float* xb = xa + (size_t)64 * IN_F;
    const __bf16* wsrc0 = Wb + (size_t)(n0 + 16 * wave + lrow) * IN_F + quad * 8;
    const __bf16* wsrc1 = wsrc0 + (size_t)64 * IN_F;
    unsigned char* ldsB0 = lds + 8192 + wave * 1024;
    unsigned char* ldsB1 = ldsB0 + 4096;
    unsigned char* wr = &lds[((srow >> 4) * 64 + sseg * 16 + (srow & 15)) * 16];
    const unsigned char* rdA = &lds[(wm >> 4) * 1024 + lane * 16];
    const unsigned char* rdB = &lds[8192 + (wn >> 4) * 1024 + lane * 16];

    f32x4 A00 = *(const f32x4*)(xa);
    f32x4 A01 = *(const f32x4*)(xa + 4);
    f32x4 A10 = *(const f32x4*)(xb);
    f32x4 A11 = *(const f32x4*)(xb + 4);
    glds16(wsrc0, ldsB0);
    glds16(wsrc1, ldsB1);
    __builtin_amdgcn_sched_barrier(0);

    int koffA = 0, koffB = 0;
    auto stageA = [&](int buf) {
        unsigned char* w = wr + buf * 16384;
        *(bf16x8*)(w +    0) = cvt8(A00, A01);
        *(bf16x8*)(w + 4096) = cvt8(A10, A11);
        koffA = (koffA + 32) & (IN_F - 1);
        A00 = *(const f32x4*)(xa + koffA); A01 = *(const f32x4*)(xa + koffA + 4);
        A10 = *(const f32x4*)(xb + koffA); A11 = *(const f32x4*)(xb + koffA + 4);
    };
    auto stageB = [&](int buf) {
        koffB += 32;
        glds16(wsrc0 + koffB, ldsB0 + buf * 16384);
        glds16(wsrc1 + koffB, ldsB1 + buf * 16384);
        __builtin_amdgcn_sched_barrier(0);
    };
    auto compute = [&](int buf) {
        const unsigned char* ra = rdA + buf * 16384;
        const unsigned char* rb = rdB + buf * 16384;
        bf16x8 af[4], bfr[4];
        #pragma unroll
        for (int t = 0; t < 4; ++t) af[t]  = *(const bf16x8*)(ra + t * 1024);
        #pragma unroll
        for (int t = 0; t < 4; ++t) bfr[t] = *(const bf16x8*)(rb + t * 1024);
        #pragma unroll
        for (int i = 0; i < 4; ++i)
            #pragma unroll
            for (int j = 0; j < 4; ++j)
                acc[i][j] = __builtin_amdgcn_mfma_f32_16x16x32_bf16(af[i], bfr[j], acc[i][j], 0, 0, 0);
    };

    #pragma unroll 1
    for (int it = 0; it < IN_F / 32 - 2; it += 2) {
        stageA(0); FBAR_CNT(); stageB(1); compute(0);
        stageA(1); FBAR_CNT(); stageB(0); compute(1);
    }
    stageA(0); FBAR_CNT(); stageB(1); compute(0);
    stageA(1); FBAR_ALL(); compute(1);

    const int s = lane & 3;
    const float kmul = (s == 0) ? -2.f : -1.f;
    const float aa   = (s == 0) ?  2.f :  1.f;
    const float cc   = (s == 0) ? -1.f :  0.f;
    const bool  is_sin  = (s == 1);
    const bool  is_relu = (s == 2);
    #pragma unroll
    for (int j = 0; j < 4; ++j) {
        const int gc = n0 + wn + j * 16 + lrow;
        const float bvv = bias[gc];
        #pragma unroll
        for (int i = 0; i < 4; ++i) {
            const int gr0 = m0 + wm + i * 16 + quad * 4;
            float* op = O + (size_t)gr0 * OUT_F + gc;
            #pragma unroll
            for (int r = 0; r < 4; ++r) {
                const float y = acc[i][j][r] + bvv;
                const float e = __expf(kmul * y);
                const float g = fmaf(aa, __builtin_amdgcn_rcpf(1.f + e), cc);
                const float sv = __sinf(y);
                const float rv = fmaxf(y, 0.f);
                const float res = is_sin ? sv : (is_relu ? rv : g);
                op[(size_t)r * OUT_F] = res;
            }
        }
    }
}

extern "C" void kernel_launch(void* const* d_in, const int* in_sizes, int n_in,
                              void* d_out, int out_size, void* d_ws, size_t ws_size,
                              hipStream_t stream) {
    const float* X = (const float*)d_in[0];
    const float* W = (const float*)d_in[1];
    const float* b = (const float*)d_in[2];
    float* O = (float*)d_out;

    const size_t nX = (size_t)B_ROWS * IN_F;
    const size_t nW = (size_t)OUT_F * IN_F;
    const size_t need = (nX + nW) * sizeof(__bf16);

    if (ws_size >= need) {
        __bf16* Xb = (__bf16*)d_ws;
        __bf16* Wb = Xb + nX;
        const int xblocks = (int)(nX / (256 * 16));   // 16384
        const int wblocks = (int)(nW / (256 * 16));   // 256
        cvt_all<<<xblocks + wblocks, 256, 0, stream>>>(X, W, Xb, Wb);
        const int grid = (B_ROWS / BM) * (OUT_F / BN);  // 1024
        fused_linear_act<<<grid, BDIM, 0, stream>>>(Xb, Wb, b, O);
    } else {
        __bf16* Wb = (__bf16*)d_ws;  // 2 MB
        w_to_bf16<<<(int)(nW / (256 * 16)), 256, 0, stream>>>(W, Wb);
        const int grid = (B_ROWS / 128) * (OUT_F / 128);  // 4096
        fused_linear_act_f32a<<<grid, FBDIM, 0, stream>>>(X, Wb, b, O);
    }
}